// Round 10
// baseline (815.646 us; speedup 1.0000x reference)
//
#include <hip/hip_runtime.h>

#define K_DIM 128

typedef __attribute__((ext_vector_type(8))) short short8;
typedef __attribute__((ext_vector_type(4))) float f32x4;

// ---- compile-time path tables: PATHS order = l1-major, l2, l3 ascending ----
constexpr int C_L1[34] = {0,0,0,0, 1,1,1,1,1,1,1,1,1, 2,2,2,2,2,2,2,2,2,2,2, 3,3,3,3,3,3,3,3,3,3};
constexpr int C_L2[34] = {0,1,2,3, 0,1,1,1,2,2,2,3,3, 0,1,1,1,2,2,2,2,3,3,3, 0,1,1,2,2,2,3,3,3,3};
constexpr int C_L3[34] = {0,1,2,3, 1,0,1,2,1,2,3,2,3, 2,1,2,3,0,1,2,3,1,2,3, 3,2,3,1,2,3,0,1,2,3};
constexpr int C_NP[4]  = {4,9,11,10};
constexpr int C_PL[4][11] = {
  {0,5,17,30, 0,0,0,0,0,0,0},
  {1,4,6,8,14,18,21,27,31, 0,0},
  {2,7,9,11,13,15,19,22,25,28,32},
  {3,10,12,16,20,23,24,26,29,33, 0}
};
constexpr int C_CSUM[4] = {0,8,26,48};      // 64-ch chunk base per l3
constexpr size_t FOFF[4] = {0, 1048576, 4194304, 9437184};  // per-l elem offsets
constexpr int FSZ[4] = {1048576, 3145728, 5242880, 7340032};
constexpr size_t FTOT = 16777216;           // elems per f-set

__device__ double dfactd(int n){ double r=1.0; for(int i=2;i<=n;++i) r*=(double)i; return r; }

__device__ __forceinline__ unsigned short f2bf(float x) {
    unsigned int b = __float_as_uint(x);
    return (unsigned short)((b + 0x7FFFu + ((b >> 16) & 1u)) >> 16);
}

// packed RNE f32x2 -> bf16x2 (single VALU inst; pure-ALU asm)
__device__ __forceinline__ unsigned int cvtpk(float lo, float hi) {
    unsigned int r;
    asm("v_cvt_pk_bf16_f32 %0, %1, %2" : "=v"(r) : "v"(lo), "v"(hi));
    return r;
}

// C2[p][m1i][m2i], 34*49 floats at d_ws+0
__global__ void cg_init(float* __restrict__ C2) {
    int e = blockIdx.x*blockDim.x + threadIdx.x;
    if (e >= 34*49) return;
    int p = e/49, r = e%49, m1i = r/7, m2i = r%7;
    int l1 = C_L1[p], l2 = C_L2[p], l3 = C_L3[p];
    float val = 0.f;
    if (m1i < 2*l1+1 && m2i < 2*l2+1) {
        int m1 = m1i-l1, m2 = m2i-l2, m3 = m1+m2;
        if (m3 >= -l3 && m3 <= l3) {
            double pref = sqrt((double)(2*l3+1) * dfactd(l3+l1-l2)*dfactd(l3-l1+l2)
                               * dfactd(l1+l2-l3) / dfactd(l1+l2+l3+1));
            pref *= sqrt(dfactd(l3+m3)*dfactd(l3-m3)*dfactd(l1-m1)*dfactd(l1+m1)
                         *dfactd(l2-m2)*dfactd(l2+m2));
            int kmin = max(0, max(l2-l3-m1, l1-l3+m2));
            int kmax = min(l1+l2-l3, min(l1-m1, l2+m2));
            double s = 0.0;
            for (int k=kmin;k<=kmax;++k) {
                double t = dfactd(k)*dfactd(l1+l2-l3-k)*dfactd(l1-m1-k)
                         * dfactd(l2+m2-k)*dfactd(l3-l2+m1+k)*dfactd(l3-l1-m2+k);
                s += ((k&1)? -1.0:1.0)/t;
            }
            val = (float)(pref*s);
        }
    }
    C2[e] = val;
}

// W -> bf16 transposed+swizzled tiles: chunk c: byte col*128 + (2kk ^ ((col&7)<<4))
__global__ void wt_prep(const float* __restrict__ W0, const float* __restrict__ W1,
                        const float* __restrict__ W2, const float* __restrict__ W3,
                        unsigned short* __restrict__ wt) {
    int b = blockIdx.x;
    int chunk = b >> 5;
    int e = ((b & 31) << 8) + threadIdx.x;
    int kk = e & 63, col = e >> 6;
    int l3 = (chunk < 8) ? 0 : (chunk < 26) ? 1 : (chunk < 48) ? 2 : 3;
    int local = chunk - C_CSUM[l3];
    int kin = local*64 + kk;
    const float* W = (l3==0)?W0:(l3==1)?W1:(l3==2)?W2:W3;
    float v = W[(size_t)kin*K_DIM + col];
    wt[(size_t)chunk*8192 + col*64 + (kk ^ ((col&7)<<3))] = f2bf(v);
}

// f1/f2 -> bf16 packed copies in ws
__global__ void fpack(const float* __restrict__ s0, const float* __restrict__ s1,
                      const float* __restrict__ s2, const float* __restrict__ s3,
                      const float* __restrict__ s4, const float* __restrict__ s5,
                      const float* __restrict__ s6, const float* __restrict__ s7,
                      unsigned short* __restrict__ dst) {
    int y = blockIdx.y;
    int l = y & 3, fi = y >> 2;
    const float* srcs[8] = {s0,s1,s2,s3,s4,s5,s6,s7};
    const float* src = srcs[y];
    int i4 = blockIdx.x*256 + threadIdx.x;
    if (i4*4 >= FSZ[l]) return;
    float4 v = reinterpret_cast<const float4*>(src)[i4];
    unsigned int u0 = (unsigned int)f2bf(v.x) | ((unsigned int)f2bf(v.y) << 16);
    unsigned int u1 = (unsigned int)f2bf(v.z) | ((unsigned int)f2bf(v.w) << 16);
    unsigned short* d = dst + fi*FTOT + FOFF[l] + (size_t)i4*4;
    *reinterpret_cast<uint2*>(d) = make_uint2(u0, u1);
}

#define DO_DW(i, u, v) { \
    float x0 = __uint_as_float((u)<<16); \
    float x1 = __uint_as_float((u)&0xFFFF0000u); \
    float y0 = __uint_as_float((v)<<16); \
    float y1 = __uint_as_float((v)&0xFFFF0000u); \
    a[2*(i)]   = fmaf(c*x0, y0, a[2*(i)]); \
    a[2*(i)+1] = fmaf(c*x1, y1, a[2*(i)+1]); }

// One (path, h) pair: W-load hoist, branch-free grouped-batch TP -> swizzled A
// tile, MFMA accumulate. 256 threads, 64 output rows per block.
template<int L3, int PI>
__device__ __forceinline__ void chunk_pair(
    const unsigned short* __restrict__ f1b, const unsigned short* __restrict__ f2b,
    const unsigned short* __restrict__ wt, const float* __restrict__ C2,
    float* C2s, unsigned char* Asb, unsigned char* Wtb,
    int tid, int n, int m3, int r, int chq,
    int wid, int lr, int lg, f32x4 (&acc)[8])
{
    constexpr int P  = C_PL[L3][PI];
    constexpr int l1 = C_L1[P], l2 = C_L2[P];
    constexpr int d1 = 2*l1+1, d2 = 2*l2+1;
    constexpr int G1 = (d1 <= 4) ? d1 : (d1+1)/2;   // term group sizes (<=4)

    if (tid < 49) C2s[tid] = C2[P*49 + tid];

    #pragma unroll
    for (int h = 0; h < 2; ++h) {
        __syncthreads();   // prev MFMA done; C2s visible
        // ---- issue W-tile global loads early (in flight during TP) ----
        const float4* wsrc = reinterpret_cast<const float4*>(
            wt + (size_t)(C_CSUM[L3] + PI*2 + h) * 8192);
        float4 w0 = wsrc[tid];
        float4 w1 = wsrc[tid + 256];
        float4 w2 = wsrc[tid + 512];
        float4 w3 = wsrc[tid + 768];
        // ---- TP: branch-free. cf=0 kills invalid terms; offsets clamped. ----
        float a[16];
        #pragma unroll
        for (int j=0;j<16;++j) a[j] = 0.f;
        {
            const unsigned short* bp1 = f1b + FOFF[l1] + (size_t)n*(d1*128) + h*64 + chq;
            const unsigned short* bp2 = f2b + FOFF[l2] + (size_t)n*(d2*128) + h*64 + chq;
            float cf[d1];
            int   o2[d1];
            #pragma unroll
            for (int t=0;t<d1;++t) {
                int m2i = m3 + (l1 + l2) - t;
                bool ok = (m2i >= 0) && (m2i < d2);
                cf[t] = ok ? C2s[t*7 + m2i] : 0.f;
                o2[t] = (ok ? m2i : 0) * 128;
            }
            // group 1: batch-load all terms' 4 slices, then FMA
            {
                uint4 qa[G1], qb[G1], ra[G1], rb[G1];
                #pragma unroll
                for (int t=0;t<G1;++t) {
                    qa[t] = *reinterpret_cast<const uint4*>(bp1 + t*128);
                    qb[t] = *reinterpret_cast<const uint4*>(bp1 + t*128 + 8);
                    ra[t] = *reinterpret_cast<const uint4*>(bp2 + o2[t]);
                    rb[t] = *reinterpret_cast<const uint4*>(bp2 + o2[t] + 8);
                }
                #pragma unroll
                for (int t=0;t<G1;++t) {
                    float c = cf[t];
                    DO_DW(0, qa[t].x, ra[t].x)  DO_DW(1, qa[t].y, ra[t].y)
                    DO_DW(2, qa[t].z, ra[t].z)  DO_DW(3, qa[t].w, ra[t].w)
                    DO_DW(4, qb[t].x, rb[t].x)  DO_DW(5, qb[t].y, rb[t].y)
                    DO_DW(6, qb[t].z, rb[t].z)  DO_DW(7, qb[t].w, rb[t].w)
                }
            }
            // group 2 (only for d1>4)
            if constexpr (G1 < d1) {
                constexpr int G2 = d1 - G1;
                uint4 qa[G2], qb[G2], ra[G2], rb[G2];
                #pragma unroll
                for (int t=0;t<G2;++t) {
                    qa[t] = *reinterpret_cast<const uint4*>(bp1 + (G1+t)*128);
                    qb[t] = *reinterpret_cast<const uint4*>(bp1 + (G1+t)*128 + 8);
                    ra[t] = *reinterpret_cast<const uint4*>(bp2 + o2[G1+t]);
                    rb[t] = *reinterpret_cast<const uint4*>(bp2 + o2[G1+t] + 8);
                }
                #pragma unroll
                for (int t=0;t<G2;++t) {
                    float c = cf[G1+t];
                    DO_DW(0, qa[t].x, ra[t].x)  DO_DW(1, qa[t].y, ra[t].y)
                    DO_DW(2, qa[t].z, ra[t].z)  DO_DW(3, qa[t].w, ra[t].w)
                    DO_DW(4, qb[t].x, rb[t].x)  DO_DW(5, qb[t].y, rb[t].y)
                    DO_DW(6, qb[t].z, rb[t].z)  DO_DW(7, qb[t].w, rb[t].w)
                }
            }
        }
        // pack to bf16 (v_cvt_pk) + swizzled LDS write (2 x b128)
        unsigned int pk[8];
        #pragma unroll
        for (int j=0;j<8;++j) pk[j] = cvtpk(a[2*j], a[2*j+1]);
        {
            int ab = r*128, g0 = chq*2, key = (r&7)<<4;
            *reinterpret_cast<uint4*>(Asb + ab + ( g0        ^ key)) = make_uint4(pk[0],pk[1],pk[2],pk[3]);
            *reinterpret_cast<uint4*>(Asb + ab + ((g0 + 16)  ^ key)) = make_uint4(pk[4],pk[5],pk[6],pk[7]);
        }
        // ---- W LDS write (loads issued above have had TP to land) ----
        {
            float4* dst = reinterpret_cast<float4*>(Wtb);
            dst[tid]       = w0;
            dst[tid + 256] = w1;
            dst[tid + 512] = w2;
            dst[tid + 768] = w3;
        }
        __syncthreads();
        // ---- MFMA: 2 K=32 steps, 1 row-tile (wid) x 8 col-tiles per wave ----
        #pragma unroll
        for (int ks=0; ks<2; ++ks) {
            const int kb = 16*lg + 64*ks;
            const int arow = 16*wid + lr;
            short8 af = *reinterpret_cast<const short8*>(
                Asb + arow*128 + (kb ^ ((arow&7)<<4)));
            #pragma unroll
            for (int cc=0; cc<8; ++cc) {
                int col = 16*cc + lr;
                short8 bf = *reinterpret_cast<const short8*>(
                    Wtb + col*128 + (kb ^ ((col&7)<<4)));
                acc[cc] = __builtin_amdgcn_mfma_f32_16x16x32_bf16(af, bf, acc[cc], 0, 0, 0);
            }
        }
    }
}

template<int L3, int PI>
__device__ __forceinline__ void paths_from(
    const unsigned short* __restrict__ f1b, const unsigned short* __restrict__ f2b,
    const unsigned short* __restrict__ wt, const float* __restrict__ C2,
    float* C2s, unsigned char* Asb, unsigned char* Wtb,
    int tid, int n, int m3, int r, int chq,
    int wid, int lr, int lg, f32x4 (&acc)[8])
{
    if constexpr (PI < C_NP[L3]) {
        chunk_pair<L3, PI>(f1b, f2b, wt, C2, C2s, Asb, Wtb,
                           tid, n, m3, r, chq, wid, lr, lg, acc);
        paths_from<L3, PI+1>(f1b, f2b, wt, C2, C2s, Asb, Wtb,
                             tid, n, m3, r, chq, wid, lr, lg, acc);
    }
}

template<int L3>
__device__ __forceinline__ void run_l3(
    int rb,
    const unsigned short* __restrict__ f1b, const unsigned short* __restrict__ f2b,
    const unsigned short* __restrict__ wt, const float* __restrict__ C2,
    float* __restrict__ out,
    float* C2s, unsigned char* Asb, unsigned char* Wtb)
{
    constexpr int TL3 = 2*L3+1;
    const int tid = threadIdx.x;
    const int row0 = rb*64;
    const int r   = tid >> 2;          // TP row 0..63
    const int chq = (tid & 3) * 16;    // TP ch base within 64-half
    const int gr  = row0 + r;
    const int n   = gr / TL3;
    const int m3  = (gr - n*TL3) - L3;
    const int lane = tid & 63, wid = tid >> 6;   // wid 0..3 = row-tile
    const int lr = lane & 15, lg = lane >> 4;
    constexpr size_t OB = FOFF[L3];

    f32x4 acc[8];
    #pragma unroll
    for (int c=0;c<8;++c) acc[c] = (f32x4){0.f,0.f,0.f,0.f};

    paths_from<L3, 0>(f1b, f2b, wt, C2, C2s, Asb, Wtb,
                      tid, n, m3, r, chq, wid, lr, lg, acc);

    // epilogue: residual (bf16 f1) + store. D: col=lane&15, row=4*(lane>>4)+i
    const unsigned short* __restrict__ fr = f1b + OB;
    #pragma unroll
    for (int i=0;i<4;++i) {
        int rr = 16*wid + 4*lg + i;
        size_t ro = (size_t)(row0 + rr) * K_DIM;
        #pragma unroll
        for (int cc=0;cc<8;++cc) {
            int col = 16*cc + lr;
            float res = __uint_as_float((unsigned int)fr[ro + col] << 16);
            out[OB + ro + col] = res + acc[cc][i];
        }
    }
}

__global__ __launch_bounds__(256, 4) void cg_main(
    const unsigned short* __restrict__ f1b, const unsigned short* __restrict__ f2b,
    const unsigned short* __restrict__ wt,
    const float* __restrict__ C2, float* __restrict__ out)
{
    __shared__ __align__(16) unsigned char Asb[64*128];   // 8 KB
    __shared__ __align__(16) unsigned char Wtb[128*128];  // 16 KB
    __shared__ float C2s[49];

    // XCD-aware + L2-locality schedule: x = XCD, j in [0,256) per XCD.
    // 16 rounds of 16 blocks {1,3,5,7 per l3}; round r's blocks (all l3) cover
    // nodes [64r, 64r+64) of this XCD's slice -> 512KB f-data, L2-resident.
    int bid = blockIdx.x;
    int x = bid & 7, j = bid >> 3;
    int rnd = j >> 4, k = j & 15;
    if (k == 0)
        run_l3<0>(x*16  + rnd,            f1b, f2b, wt, C2, out, C2s, Asb, Wtb);
    else if (k < 4)
        run_l3<1>(x*48  + 3*rnd + (k-1),  f1b, f2b, wt, C2, out, C2s, Asb, Wtb);
    else if (k < 9)
        run_l3<2>(x*80  + 5*rnd + (k-4),  f1b, f2b, wt, C2, out, C2s, Asb, Wtb);
    else
        run_l3<3>(x*112 + 7*rnd + (k-9),  f1b, f2b, wt, C2, out, C2s, Asb, Wtb);
}

extern "C" void kernel_launch(void* const* d_in, const int* in_sizes, int n_in,
                              void* d_out, int out_size, void* d_ws, size_t ws_size,
                              hipStream_t stream) {
    const float* f10 = (const float*)d_in[0];
    const float* f20 = (const float*)d_in[1];
    const float* W0  = (const float*)d_in[2];
    const float* f11 = (const float*)d_in[3];
    const float* f21 = (const float*)d_in[4];
    const float* W1  = (const float*)d_in[5];
    const float* f12 = (const float*)d_in[6];
    const float* f22 = (const float*)d_in[7];
    const float* W2  = (const float*)d_in[8];
    const float* f13 = (const float*)d_in[9];
    const float* f23 = (const float*)d_in[10];
    const float* W3  = (const float*)d_in[11];

    float* C2 = (float*)d_ws;                                       // 6664 B
    unsigned short* wtw = (unsigned short*)((char*)d_ws + 8192);    // 1.09 MB
    unsigned short* f1b = (unsigned short*)((char*)d_ws + 1122304); // 32 MB
    unsigned short* f2b = f1b + FTOT;                               // 32 MB
    float* out = (float*)d_out;

    hipLaunchKernelGGL(cg_init, dim3(7), dim3(256), 0, stream, C2);
    hipLaunchKernelGGL(wt_prep, dim3(68*32), dim3(256), 0, stream, W0, W1, W2, W3, wtw);
    hipLaunchKernelGGL(fpack, dim3(7168, 8), dim3(256), 0, stream,
        f10, f11, f12, f13, f20, f21, f22, f23, f1b);
    hipLaunchKernelGGL(cg_main, dim3(2048), dim3(256), 0, stream,
        f1b, f2b, wtw, C2, out);
}

// Round 11
// 533.345 us; speedup vs baseline: 1.5293x; 1.5293x over previous
//
#include <hip/hip_runtime.h>

#define K_DIM 128

typedef __attribute__((ext_vector_type(8))) short short8;
typedef __attribute__((ext_vector_type(4))) float f32x4;

// ---- compile-time path tables: PATHS order = l1-major, l2, l3 ascending ----
constexpr int C_L1[34] = {0,0,0,0, 1,1,1,1,1,1,1,1,1, 2,2,2,2,2,2,2,2,2,2,2, 3,3,3,3,3,3,3,3,3,3};
constexpr int C_L2[34] = {0,1,2,3, 0,1,1,1,2,2,2,3,3, 0,1,1,1,2,2,2,2,3,3,3, 0,1,1,2,2,2,3,3,3,3};
constexpr int C_L3[34] = {0,1,2,3, 1,0,1,2,1,2,3,2,3, 2,1,2,3,0,1,2,3,1,2,3, 3,2,3,1,2,3,0,1,2,3};
constexpr int C_NP[4]  = {4,9,11,10};
constexpr int C_PL[4][11] = {
  {0,5,17,30, 0,0,0,0,0,0,0},
  {1,4,6,8,14,18,21,27,31, 0,0},
  {2,7,9,11,13,15,19,22,25,28,32},
  {3,10,12,16,20,23,24,26,29,33, 0}
};
constexpr int C_CSUM[4] = {0,8,26,48};      // 64-ch chunk base per l3
constexpr size_t FOFF[4] = {0, 1048576, 4194304, 9437184};  // per-l elem offsets
constexpr int FSZ[4] = {1048576, 3145728, 5242880, 7340032};
constexpr size_t FTOT = 16777216;           // elems per f-set

__device__ double dfactd(int n){ double r=1.0; for(int i=2;i<=n;++i) r*=(double)i; return r; }

__device__ __forceinline__ unsigned short f2bf(float x) {
    unsigned int b = __float_as_uint(x);
    return (unsigned short)((b + 0x7FFFu + ((b >> 16) & 1u)) >> 16);
}

// packed RNE f32x2 -> bf16x2 (single VALU inst; pure-ALU asm)
__device__ __forceinline__ unsigned int cvtpk(float lo, float hi) {
    unsigned int r;
    asm("v_cvt_pk_bf16_f32 %0, %1, %2" : "=v"(r) : "v"(lo), "v"(hi));
    return r;
}

// C2[p][m1i][m2i], 34*49 floats at d_ws+0
__global__ void cg_init(float* __restrict__ C2) {
    int e = blockIdx.x*blockDim.x + threadIdx.x;
    if (e >= 34*49) return;
    int p = e/49, r = e%49, m1i = r/7, m2i = r%7;
    int l1 = C_L1[p], l2 = C_L2[p], l3 = C_L3[p];
    float val = 0.f;
    if (m1i < 2*l1+1 && m2i < 2*l2+1) {
        int m1 = m1i-l1, m2 = m2i-l2, m3 = m1+m2;
        if (m3 >= -l3 && m3 <= l3) {
            double pref = sqrt((double)(2*l3+1) * dfactd(l3+l1-l2)*dfactd(l3-l1+l2)
                               * dfactd(l1+l2-l3) / dfactd(l1+l2+l3+1));
            pref *= sqrt(dfactd(l3+m3)*dfactd(l3-m3)*dfactd(l1-m1)*dfactd(l1+m1)
                         *dfactd(l2-m2)*dfactd(l2+m2));
            int kmin = max(0, max(l2-l3-m1, l1-l3+m2));
            int kmax = min(l1+l2-l3, min(l1-m1, l2+m2));
            double s = 0.0;
            for (int k=kmin;k<=kmax;++k) {
                double t = dfactd(k)*dfactd(l1+l2-l3-k)*dfactd(l1-m1-k)
                         * dfactd(l2+m2-k)*dfactd(l3-l2+m1+k)*dfactd(l3-l1-m2+k);
                s += ((k&1)? -1.0:1.0)/t;
            }
            val = (float)(pref*s);
        }
    }
    C2[e] = val;
}

// W -> bf16 transposed+swizzled tiles: chunk c elem col*64 + (kk ^ ((col&7)<<3))
// => byte col*128 + (2kk ^ ((col&7)<<4))
__global__ void wt_prep(const float* __restrict__ W0, const float* __restrict__ W1,
                        const float* __restrict__ W2, const float* __restrict__ W3,
                        unsigned short* __restrict__ wt) {
    int b = blockIdx.x;
    int chunk = b >> 5;
    int e = ((b & 31) << 8) + threadIdx.x;
    int kk = e & 63, col = e >> 6;
    int l3 = (chunk < 8) ? 0 : (chunk < 26) ? 1 : (chunk < 48) ? 2 : 3;
    int local = chunk - C_CSUM[l3];
    int kin = local*64 + kk;
    const float* W = (l3==0)?W0:(l3==1)?W1:(l3==2)?W2:W3;
    float v = W[(size_t)kin*K_DIM + col];
    wt[(size_t)chunk*8192 + col*64 + (kk ^ ((col&7)<<3))] = f2bf(v);
}

// f1/f2 -> bf16 packed copies in ws
__global__ void fpack(const float* __restrict__ s0, const float* __restrict__ s1,
                      const float* __restrict__ s2, const float* __restrict__ s3,
                      const float* __restrict__ s4, const float* __restrict__ s5,
                      const float* __restrict__ s6, const float* __restrict__ s7,
                      unsigned short* __restrict__ dst) {
    int y = blockIdx.y;
    int l = y & 3, fi = y >> 2;
    const float* srcs[8] = {s0,s1,s2,s3,s4,s5,s6,s7};
    const float* src = srcs[y];
    int i4 = blockIdx.x*256 + threadIdx.x;
    if (i4*4 >= FSZ[l]) return;
    float4 v = reinterpret_cast<const float4*>(src)[i4];
    unsigned int u0 = (unsigned int)f2bf(v.x) | ((unsigned int)f2bf(v.y) << 16);
    unsigned int u1 = (unsigned int)f2bf(v.z) | ((unsigned int)f2bf(v.w) << 16);
    unsigned short* d = dst + fi*FTOT + FOFF[l] + (size_t)i4*4;
    *reinterpret_cast<uint2*>(d) = make_uint2(u0, u1);
}

#define DO_DW(i, u, v) { \
    float x0 = __uint_as_float((u)<<16); \
    float x1 = __uint_as_float((u)&0xFFFF0000u); \
    float y0 = __uint_as_float((v)<<16); \
    float y1 = __uint_as_float((v)&0xFFFF0000u); \
    a[2*(i)]   = fmaf(c*x0, y0, a[2*(i)]); \
    a[2*(i)+1] = fmaf(c*x1, y1, a[2*(i)+1]); }

// ---------- staged pair (l3>=1): 16-node block, f rows -> LDS once ----------
template<int L3, int PI>
__device__ __forceinline__ void staged_pair(
    const unsigned short* __restrict__ f1b, const unsigned short* __restrict__ f2b,
    const unsigned short* __restrict__ wt, const float* __restrict__ C2,
    float* C2s, unsigned char* f1s, unsigned char* f2s, unsigned char* Asb,
    int tid, int n0, int wid, int lr, int lg, f32x4 (&acc)[2*L3+1][2])
{
    constexpr int P  = C_PL[L3][PI];
    constexpr int l1 = C_L1[P], l2 = C_L2[P];
    constexpr int d1 = 2*l1+1, d2 = 2*l2+1;
    constexpr int TL3  = 2*L3+1;
    constexpr int ROWS = 16*TL3;
    constexpr int CNT1 = 128*d1;    // uint4 slots (16 nodes * d1 rows * 8)
    constexpr int CNT2 = 128*d2;

    if (tid < 49) C2s[tid] = C2[P*49 + tid];

    #pragma unroll
    for (int h = 0; h < 2; ++h) {
        __syncthreads();   // prev TP reads of f1s/f2s + MFMA reads of Asb done
        // ---- W fragments straight from global (pre-swizzled), issue early ----
        const unsigned char* wbase = (const unsigned char*)
            (wt + (size_t)(C_CSUM[L3] + PI*2 + h) * 8192);
        const int col0 = 16*(2*wid)   + lr;
        const int col1 = 16*(2*wid+1) + lr;
        short8 wf00 = *reinterpret_cast<const short8*>(wbase + col0*128 + ((16*lg     ) ^ ((col0&7)<<4)));
        short8 wf01 = *reinterpret_cast<const short8*>(wbase + col0*128 + ((16*lg + 64) ^ ((col0&7)<<4)));
        short8 wf10 = *reinterpret_cast<const short8*>(wbase + col1*128 + ((16*lg     ) ^ ((col1&7)<<4)));
        short8 wf11 = *reinterpret_cast<const short8*>(wbase + col1*128 + ((16*lg + 64) ^ ((col1&7)<<4)));
        // ---- stage f1/f2 rows (coalesced, swizzled LDS) ----
        const unsigned short* g1 = f1b + FOFF[l1] + (size_t)n0*(d1*128) + h*64;
        const unsigned short* g2 = f2b + FOFF[l2] + (size_t)n0*(d2*128) + h*64;
        #pragma unroll
        for (int it=0; it*256 < CNT1; ++it) {
            int u = tid + it*256;
            if (u < CNT1) {
                int rowl = u >> 3, cq = u & 7;
                uint4 v = *reinterpret_cast<const uint4*>(g1 + rowl*128 + cq*8);
                *reinterpret_cast<uint4*>(f1s + rowl*128 + ((cq*16) ^ ((rowl&7)<<4))) = v;
            }
        }
        #pragma unroll
        for (int it=0; it*256 < CNT2; ++it) {
            int u = tid + it*256;
            if (u < CNT2) {
                int rowl = u >> 3, cq = u & 7;
                uint4 v = *reinterpret_cast<const uint4*>(g2 + rowl*128 + cq*8);
                *reinterpret_cast<uint4*>(f2s + rowl*128 + ((cq*16) ^ ((rowl&7)<<4))) = v;
            }
        }
        __syncthreads();   // f-stage + C2s visible
        // ---- TP from LDS: slot = (row, 16ch-chunk), ROWS*4 slots ----
        #pragma unroll
        for (int it=0; it*256 < ROWS*4; ++it) {
            int s = tid + it*256;
            if (s < ROWS*4) {
                int row = s >> 2, chq = s & 3;
                int nl  = row / TL3;
                int m3  = row - nl*TL3 - L3;
                float a[16];
                #pragma unroll
                for (int j=0;j<16;++j) a[j] = 0.f;
                #pragma unroll
                for (int t=0; t<d1; ++t) {
                    int m2i = m3 + (l1 + l2) - t;
                    bool ok = (m2i >= 0) && (m2i < d2);
                    float c = ok ? C2s[t*7 + m2i] : 0.f;
                    int rl1 = nl*d1 + t;
                    int rl2 = nl*d2 + (ok ? m2i : 0);
                    int k1 = (rl1&7)<<4, k2 = (rl2&7)<<4;
                    uint4 qa = *reinterpret_cast<const uint4*>(f1s + rl1*128 + ((chq*32     ) ^ k1));
                    uint4 qb = *reinterpret_cast<const uint4*>(f1s + rl1*128 + ((chq*32 + 16) ^ k1));
                    uint4 ra = *reinterpret_cast<const uint4*>(f2s + rl2*128 + ((chq*32     ) ^ k2));
                    uint4 rb = *reinterpret_cast<const uint4*>(f2s + rl2*128 + ((chq*32 + 16) ^ k2));
                    DO_DW(0, qa.x, ra.x)  DO_DW(1, qa.y, ra.y)
                    DO_DW(2, qa.z, ra.z)  DO_DW(3, qa.w, ra.w)
                    DO_DW(4, qb.x, rb.x)  DO_DW(5, qb.y, rb.y)
                    DO_DW(6, qb.z, rb.z)  DO_DW(7, qb.w, rb.w)
                }
                unsigned int pk[8];
                #pragma unroll
                for (int j=0;j<8;++j) pk[j] = cvtpk(a[2*j], a[2*j+1]);
                int ab = row*128, key = (row&7)<<4;
                *reinterpret_cast<uint4*>(Asb + ab + ((chq*32     ) ^ key)) = make_uint4(pk[0],pk[1],pk[2],pk[3]);
                *reinterpret_cast<uint4*>(Asb + ab + ((chq*32 + 16) ^ key)) = make_uint4(pk[4],pk[5],pk[6],pk[7]);
            }
        }
        __syncthreads();   // Asb visible (W frags drained by compiler vmcnt)
        // ---- MFMA: TL3 row-tiles x 2 col-tiles x 2 K-steps per wave ----
        #pragma unroll
        for (int ks=0; ks<2; ++ks) {
            #pragma unroll
            for (int mt=0; mt<TL3; ++mt) {
                int arow = 16*mt + lr;
                short8 af = *reinterpret_cast<const short8*>(
                    Asb + arow*128 + ((16*lg + 64*ks) ^ ((arow&7)<<4)));
                acc[mt][0] = __builtin_amdgcn_mfma_f32_16x16x32_bf16(
                    af, ks ? wf01 : wf00, acc[mt][0], 0, 0, 0);
                acc[mt][1] = __builtin_amdgcn_mfma_f32_16x16x32_bf16(
                    af, ks ? wf11 : wf10, acc[mt][1], 0, 0, 0);
            }
        }
    }
}

template<int L3, int PI>
__device__ __forceinline__ void staged_paths(
    const unsigned short* __restrict__ f1b, const unsigned short* __restrict__ f2b,
    const unsigned short* __restrict__ wt, const float* __restrict__ C2,
    float* C2s, unsigned char* f1s, unsigned char* f2s, unsigned char* Asb,
    int tid, int n0, int wid, int lr, int lg, f32x4 (&acc)[2*L3+1][2])
{
    if constexpr (PI < C_NP[L3]) {
        staged_pair<L3, PI>(f1b, f2b, wt, C2, C2s, f1s, f2s, Asb,
                            tid, n0, wid, lr, lg, acc);
        staged_paths<L3, PI+1>(f1b, f2b, wt, C2, C2s, f1s, f2s, Asb,
                               tid, n0, wid, lr, lg, acc);
    }
}

template<int L3>
__device__ __forceinline__ void run_staged(
    int n0,
    const unsigned short* __restrict__ f1b, const unsigned short* __restrict__ f2b,
    const unsigned short* __restrict__ wt, const float* __restrict__ C2,
    float* __restrict__ out,
    float* C2s, unsigned char* f1s, unsigned char* f2s, unsigned char* Asb)
{
    constexpr int TL3 = 2*L3+1;
    const int tid  = threadIdx.x;
    const int lane = tid & 63, wid = tid >> 6;
    const int lr   = lane & 15, lg = lane >> 4;
    constexpr size_t OB = FOFF[L3];

    f32x4 acc[TL3][2];
    #pragma unroll
    for (int mt=0; mt<TL3; ++mt) {
        acc[mt][0] = (f32x4){0.f,0.f,0.f,0.f};
        acc[mt][1] = (f32x4){0.f,0.f,0.f,0.f};
    }

    staged_paths<L3, 0>(f1b, f2b, wt, C2, C2s, f1s, f2s, Asb,
                        tid, n0, wid, lr, lg, acc);

    // epilogue: residual (bf16 f1) + store. D: col=lane&15, row=4*(lane>>4)+i
    const unsigned short* __restrict__ fr = f1b + OB;
    #pragma unroll
    for (int mt=0; mt<TL3; ++mt) {
        #pragma unroll
        for (int j=0; j<2; ++j) {
            int col = 16*(2*wid+j) + lr;
            #pragma unroll
            for (int i=0;i<4;++i) {
                size_t ro = (size_t)(n0*TL3 + 16*mt + 4*lg + i) * K_DIM;
                float res = __uint_as_float((unsigned int)fr[ro + col] << 16);
                out[OB + ro + col] = res + acc[mt][j][i];
            }
        }
    }
}

// ---------- direct path for l3==0 (reuse=1; 64 nodes per block) ----------
template<int PI>
__device__ __forceinline__ void direct0_paths(
    const unsigned short* __restrict__ f1b, const unsigned short* __restrict__ f2b,
    const unsigned short* __restrict__ wt, const float* __restrict__ C2,
    float* C2s, unsigned char* Asb,
    int tid, int n0, int wid, int lr, int lg, f32x4 (&acc)[4][2])
{
    if constexpr (PI < 4) {
        constexpr int P = C_PL[0][PI];
        constexpr int l = C_L1[P];
        constexpr int d = 2*l+1;
        if (tid < 49) C2s[tid] = C2[P*49 + tid];
        const int r = tid >> 2, chq = tid & 3;
        const int n = n0 + r;
        #pragma unroll
        for (int h=0; h<2; ++h) {
            __syncthreads();
            const unsigned char* wbase = (const unsigned char*)
                (wt + (size_t)(PI*2 + h) * 8192);
            const int col0 = 16*(2*wid)   + lr;
            const int col1 = 16*(2*wid+1) + lr;
            short8 wf00 = *reinterpret_cast<const short8*>(wbase + col0*128 + ((16*lg     ) ^ ((col0&7)<<4)));
            short8 wf01 = *reinterpret_cast<const short8*>(wbase + col0*128 + ((16*lg + 64) ^ ((col0&7)<<4)));
            short8 wf10 = *reinterpret_cast<const short8*>(wbase + col1*128 + ((16*lg     ) ^ ((col1&7)<<4)));
            short8 wf11 = *reinterpret_cast<const short8*>(wbase + col1*128 + ((16*lg + 64) ^ ((col1&7)<<4)));
            const unsigned short* bp1 = f1b + FOFF[l] + (size_t)n*(d*128) + h*64 + chq*16;
            const unsigned short* bp2 = f2b + FOFF[l] + (size_t)n*(d*128) + h*64 + chq*16;
            float a[16];
            #pragma unroll
            for (int j=0;j<16;++j) a[j] = 0.f;
            #pragma unroll
            for (int t=0; t<d; ++t) {          // all terms valid for l3=0
                float c = C2s[t*7 + (2*l - t)];
                uint4 qa = *reinterpret_cast<const uint4*>(bp1 + t*128);
                uint4 qb = *reinterpret_cast<const uint4*>(bp1 + t*128 + 8);
                uint4 ra = *reinterpret_cast<const uint4*>(bp2 + (2*l-t)*128);
                uint4 rb = *reinterpret_cast<const uint4*>(bp2 + (2*l-t)*128 + 8);
                DO_DW(0, qa.x, ra.x)  DO_DW(1, qa.y, ra.y)
                DO_DW(2, qa.z, ra.z)  DO_DW(3, qa.w, ra.w)
                DO_DW(4, qb.x, rb.x)  DO_DW(5, qb.y, rb.y)
                DO_DW(6, qb.z, rb.z)  DO_DW(7, qb.w, rb.w)
            }
            unsigned int pk[8];
            #pragma unroll
            for (int j=0;j<8;++j) pk[j] = cvtpk(a[2*j], a[2*j+1]);
            {
                int ab = r*128, key = (r&7)<<4;
                *reinterpret_cast<uint4*>(Asb + ab + ((chq*32     ) ^ key)) = make_uint4(pk[0],pk[1],pk[2],pk[3]);
                *reinterpret_cast<uint4*>(Asb + ab + ((chq*32 + 16) ^ key)) = make_uint4(pk[4],pk[5],pk[6],pk[7]);
            }
            __syncthreads();
            #pragma unroll
            for (int ks=0; ks<2; ++ks) {
                #pragma unroll
                for (int mt=0; mt<4; ++mt) {
                    int arow = 16*mt + lr;
                    short8 af = *reinterpret_cast<const short8*>(
                        Asb + arow*128 + ((16*lg + 64*ks) ^ ((arow&7)<<4)));
                    acc[mt][0] = __builtin_amdgcn_mfma_f32_16x16x32_bf16(
                        af, ks ? wf01 : wf00, acc[mt][0], 0, 0, 0);
                    acc[mt][1] = __builtin_amdgcn_mfma_f32_16x16x32_bf16(
                        af, ks ? wf11 : wf10, acc[mt][1], 0, 0, 0);
                }
            }
        }
        direct0_paths<PI+1>(f1b, f2b, wt, C2, C2s, Asb, tid, n0, wid, lr, lg, acc);
    }
}

__device__ __forceinline__ void run_direct0(
    int n0,
    const unsigned short* __restrict__ f1b, const unsigned short* __restrict__ f2b,
    const unsigned short* __restrict__ wt, const float* __restrict__ C2,
    float* __restrict__ out, float* C2s, unsigned char* Asb)
{
    const int tid  = threadIdx.x;
    const int lane = tid & 63, wid = tid >> 6;
    const int lr   = lane & 15, lg = lane >> 4;

    f32x4 acc[4][2];
    #pragma unroll
    for (int mt=0; mt<4; ++mt) {
        acc[mt][0] = (f32x4){0.f,0.f,0.f,0.f};
        acc[mt][1] = (f32x4){0.f,0.f,0.f,0.f};
    }

    direct0_paths<0>(f1b, f2b, wt, C2, C2s, Asb, tid, n0, wid, lr, lg, acc);

    const unsigned short* __restrict__ fr = f1b;
    #pragma unroll
    for (int mt=0; mt<4; ++mt) {
        #pragma unroll
        for (int j=0; j<2; ++j) {
            int col = 16*(2*wid+j) + lr;
            #pragma unroll
            for (int i=0;i<4;++i) {
                size_t ro = (size_t)(n0 + 16*mt + 4*lg + i) * K_DIM;
                float res = __uint_as_float((unsigned int)fr[ro + col] << 16);
                out[ro + col] = res + acc[mt][j][i];
            }
        }
    }
}

__global__ __launch_bounds__(256, 3) void cg_main(
    const unsigned short* __restrict__ f1b, const unsigned short* __restrict__ f2b,
    const unsigned short* __restrict__ wt,
    const float* __restrict__ C2, float* __restrict__ out)
{
    __shared__ __align__(16) unsigned char f1s[14336];   // 16 nodes x <=7 rows x 128B
    __shared__ __align__(16) unsigned char f2s[14336];
    __shared__ __align__(16) unsigned char Asb[14336];   // <=112 rows x 128B
    __shared__ float C2s[49];

    // Schedule: x = XCD (bid%8); per XCD 208 blocks = 16 rounds x 13 blocks
    // {1x l3=0 (64 nodes), 4x each l3=1,2,3 (16 nodes)}; one round covers the
    // same 64-node slice for all l3 -> L2-resident f reuse.
    int bid = blockIdx.x;
    int x = bid & 7, j = bid >> 3;
    int rnd = j / 13, k = j % 13;
    int base = x*1024 + rnd*64;     // node base of this round's slice
    if (k == 0)
        run_direct0(base, f1b, f2b, wt, C2, out, C2s, Asb);
    else if (k < 5)
        run_staged<1>(base + (k-1)*16, f1b, f2b, wt, C2, out, C2s, f1s, f2s, Asb);
    else if (k < 9)
        run_staged<2>(base + (k-5)*16, f1b, f2b, wt, C2, out, C2s, f1s, f2s, Asb);
    else
        run_staged<3>(base + (k-9)*16, f1b, f2b, wt, C2, out, C2s, f1s, f2s, Asb);
}

extern "C" void kernel_launch(void* const* d_in, const int* in_sizes, int n_in,
                              void* d_out, int out_size, void* d_ws, size_t ws_size,
                              hipStream_t stream) {
    const float* f10 = (const float*)d_in[0];
    const float* f20 = (const float*)d_in[1];
    const float* W0  = (const float*)d_in[2];
    const float* f11 = (const float*)d_in[3];
    const float* f21 = (const float*)d_in[4];
    const float* W1  = (const float*)d_in[5];
    const float* f12 = (const float*)d_in[6];
    const float* f22 = (const float*)d_in[7];
    const float* W2  = (const float*)d_in[8];
    const float* f13 = (const float*)d_in[9];
    const float* f23 = (const float*)d_in[10];
    const float* W3  = (const float*)d_in[11];

    float* C2 = (float*)d_ws;                                       // 6664 B
    unsigned short* wtw = (unsigned short*)((char*)d_ws + 8192);    // 1.09 MB
    unsigned short* f1b = (unsigned short*)((char*)d_ws + 1122304); // 32 MB
    unsigned short* f2b = f1b + FTOT;                               // 32 MB
    float* out = (float*)d_out;

    hipLaunchKernelGGL(cg_init, dim3(7), dim3(256), 0, stream, C2);
    hipLaunchKernelGGL(wt_prep, dim3(68*32), dim3(256), 0, stream, W0, W1, W2, W3, wtw);
    hipLaunchKernelGGL(fpack, dim3(7168, 8), dim3(256), 0, stream,
        f10, f11, f12, f13, f20, f21, f22, f23, f1b);
    hipLaunchKernelGGL(cg_main, dim3(1664), dim3(256), 0, stream,
        f1b, f2b, wtw, C2, out);
}

// Round 12
// 192.641 us; speedup vs baseline: 4.2340x; 2.7686x over previous
//
#include <hip/hip_runtime.h>

#define K_DIM 128

typedef __attribute__((ext_vector_type(8))) short short8;
typedef __attribute__((ext_vector_type(4))) float f32x4;

// ---- compile-time path tables: PATHS order = l1-major, l2, l3 ascending ----
constexpr int C_L1[34] = {0,0,0,0, 1,1,1,1,1,1,1,1,1, 2,2,2,2,2,2,2,2,2,2,2, 3,3,3,3,3,3,3,3,3,3};
constexpr int C_L2[34] = {0,1,2,3, 0,1,1,1,2,2,2,3,3, 0,1,1,1,2,2,2,2,3,3,3, 0,1,1,2,2,2,3,3,3,3};
constexpr int C_L3[34] = {0,1,2,3, 1,0,1,2,1,2,3,2,3, 2,1,2,3,0,1,2,3,1,2,3, 3,2,3,1,2,3,0,1,2,3};
constexpr int C_NP[4]  = {4,9,11,10};
constexpr int C_PL[4][11] = {
  {0,5,17,30, 0,0,0,0,0,0,0},
  {1,4,6,8,14,18,21,27,31, 0,0},
  {2,7,9,11,13,15,19,22,25,28,32},
  {3,10,12,16,20,23,24,26,29,33, 0}
};
constexpr int C_CSUM[4] = {0,8,26,48};      // 64-ch chunk base per l3
constexpr size_t FOFF[4] = {0, 1048576, 4194304, 9437184};  // per-l elem offsets
constexpr int FSZ[4] = {1048576, 3145728, 5242880, 7340032};
constexpr size_t FTOT = 16777216;           // elems per f-set

__device__ double dfactd(int n){ double r=1.0; for(int i=2;i<=n;++i) r*=(double)i; return r; }

__device__ __forceinline__ unsigned short f2bf(float x) {
    unsigned int b = __float_as_uint(x);
    return (unsigned short)((b + 0x7FFFu + ((b >> 16) & 1u)) >> 16);
}
__device__ __forceinline__ float bflo(unsigned int u){ return __uint_as_float(u << 16); }
__device__ __forceinline__ float bfhi(unsigned int u){ return __uint_as_float(u & 0xFFFF0000u); }

// packed RNE f32x2 -> bf16x2 (single VALU inst; pure-ALU asm)
__device__ __forceinline__ unsigned int cvtpk(float lo, float hi) {
    unsigned int r;
    asm("v_cvt_pk_bf16_f32 %0, %1, %2" : "=v"(r) : "v"(lo), "v"(hi));
    return r;
}

// C2[p][m1i][m2i], 34*49 floats at d_ws+0
__global__ void cg_init(float* __restrict__ C2) {
    int e = blockIdx.x*blockDim.x + threadIdx.x;
    if (e >= 34*49) return;
    int p = e/49, r = e%49, m1i = r/7, m2i = r%7;
    int l1 = C_L1[p], l2 = C_L2[p], l3 = C_L3[p];
    float val = 0.f;
    if (m1i < 2*l1+1 && m2i < 2*l2+1) {
        int m1 = m1i-l1, m2 = m2i-l2, m3 = m1+m2;
        if (m3 >= -l3 && m3 <= l3) {
            double pref = sqrt((double)(2*l3+1) * dfactd(l3+l1-l2)*dfactd(l3-l1+l2)
                               * dfactd(l1+l2-l3) / dfactd(l1+l2+l3+1));
            pref *= sqrt(dfactd(l3+m3)*dfactd(l3-m3)*dfactd(l1-m1)*dfactd(l1+m1)
                         *dfactd(l2-m2)*dfactd(l2+m2));
            int kmin = max(0, max(l2-l3-m1, l1-l3+m2));
            int kmax = min(l1+l2-l3, min(l1-m1, l2+m2));
            double s = 0.0;
            for (int k=kmin;k<=kmax;++k) {
                double t = dfactd(k)*dfactd(l1+l2-l3-k)*dfactd(l1-m1-k)
                         * dfactd(l2+m2-k)*dfactd(l3-l2+m1+k)*dfactd(l3-l1-m2+k);
                s += ((k&1)? -1.0:1.0)/t;
            }
            val = (float)(pref*s);
        }
    }
    C2[e] = val;
}

// W -> bf16 transposed+swizzled tiles: chunk c elem col*64 + (kk ^ ((col&7)<<3))
__global__ void wt_prep(const float* __restrict__ W0, const float* __restrict__ W1,
                        const float* __restrict__ W2, const float* __restrict__ W3,
                        unsigned short* __restrict__ wt) {
    int b = blockIdx.x;
    int chunk = b >> 5;
    int e = ((b & 31) << 8) + threadIdx.x;
    int kk = e & 63, col = e >> 6;
    int l3 = (chunk < 8) ? 0 : (chunk < 26) ? 1 : (chunk < 48) ? 2 : 3;
    int local = chunk - C_CSUM[l3];
    int kin = local*64 + kk;
    const float* W = (l3==0)?W0:(l3==1)?W1:(l3==2)?W2:W3;
    float v = W[(size_t)kin*K_DIM + col];
    wt[(size_t)chunk*8192 + col*64 + (kk ^ ((col&7)<<3))] = f2bf(v);
}

// f1/f2 -> bf16 packed copies in ws
__global__ void fpack(const float* __restrict__ s0, const float* __restrict__ s1,
                      const float* __restrict__ s2, const float* __restrict__ s3,
                      const float* __restrict__ s4, const float* __restrict__ s5,
                      const float* __restrict__ s6, const float* __restrict__ s7,
                      unsigned short* __restrict__ dst) {
    int y = blockIdx.y;
    int l = y & 3, fi = y >> 2;
    const float* srcs[8] = {s0,s1,s2,s3,s4,s5,s6,s7};
    const float* src = srcs[y];
    int i4 = blockIdx.x*256 + threadIdx.x;
    if (i4*4 >= FSZ[l]) return;
    float4 v = reinterpret_cast<const float4*>(src)[i4];
    unsigned int u0 = (unsigned int)f2bf(v.x) | ((unsigned int)f2bf(v.y) << 16);
    unsigned int u1 = (unsigned int)f2bf(v.z) | ((unsigned int)f2bf(v.w) << 16);
    unsigned short* d = dst + fi*FTOT + FOFF[l] + (size_t)i4*4;
    *reinterpret_cast<uint2*>(d) = make_uint2(u0, u1);
}

// One (path, h) pair, node-mapped TP: thread = (node, 2ch). Each f row loaded
// ONCE (independent 4B loads); all TL3 outputs per node computed in registers
// with compile-time pair validity. Then swizzled A write, MFMA.
template<int L3, int PI>
__device__ __forceinline__ void node_pair(
    const unsigned short* __restrict__ f1b, const unsigned short* __restrict__ f2b,
    const unsigned short* __restrict__ wt, const float* __restrict__ C2,
    float* C2s, unsigned char* Asb,
    int tid, int n0, int wid, int lr, int lg, f32x4 (&cacc)[2*L3+1])
{
    constexpr int P  = C_PL[L3][PI];
    constexpr int l1 = C_L1[P], l2 = C_L2[P];
    constexpr int d1 = 2*l1+1, d2 = 2*l2+1;
    constexpr int TL3 = 2*L3+1;

    if (tid < 49) C2s[tid] = C2[P*49 + tid];

    const int nodel = tid >> 5;        // 0..15
    const int chq   = tid & 31;        // 2-ch chunk within 64-half

    #pragma unroll
    for (int h = 0; h < 2; ++h) {
        __syncthreads();   // prev MFMA done reading Asb; C2s visible
        // ---- f loads: one per needed row, all independent & unconditional ----
        const unsigned short* g1 = f1b + FOFF[l1] + (size_t)(n0+nodel)*(d1*128) + h*64 + chq*2;
        const unsigned short* g2 = f2b + FOFF[l2] + (size_t)(n0+nodel)*(d2*128) + h*64 + chq*2;
        unsigned int q1[d1], q2[d2];
        #pragma unroll
        for (int t=0;t<d1;++t) q1[t] = *reinterpret_cast<const unsigned int*>(g1 + t*128);
        #pragma unroll
        for (int t=0;t<d2;++t) q2[t] = *reinterpret_cast<const unsigned int*>(g2 + t*128);
        // ---- W fragments (per-wave col, pre-swizzled; in flight during TP) ----
        const unsigned char* wbase = (const unsigned char*)
            (wt + (size_t)(C_CSUM[L3] + PI*2 + h) * 8192);
        const int col = 16*wid + lr;
        const int wkey = (col&7)<<4;
        short8 wf0 = *reinterpret_cast<const short8*>(wbase + col*128 + ((16*lg     ) ^ wkey));
        short8 wf1 = *reinterpret_cast<const short8*>(wbase + col*128 + ((16*lg + 64) ^ wkey));
        // ---- TP: all TL3 outputs for this node, static pair loop ----
        float a[TL3][2];
        #pragma unroll
        for (int mt=0;mt<TL3;++mt) { a[mt][0]=0.f; a[mt][1]=0.f; }
        #pragma unroll
        for (int m2i=0; m2i<d2; ++m2i) {
            float y0 = bflo(q2[m2i]), y1 = bfhi(q2[m2i]);
            #pragma unroll
            for (int m1i=0; m1i<d1; ++m1i) {
                int mt = (m1i-l1) + (m2i-l2) + L3;
                if (mt >= 0 && mt < TL3) {       // compile-time after unroll
                    float c = C2s[m1i*7 + m2i];
                    a[mt][0] = fmaf(c*bflo(q1[m1i]), y0, a[mt][0]);
                    a[mt][1] = fmaf(c*bfhi(q1[m1i]), y1, a[mt][1]);
                }
            }
        }
        // ---- pack + swizzled A write (b32, conflict-free) ----
        #pragma unroll
        for (int mt=0; mt<TL3; ++mt) {
            int row = nodel*TL3 + mt;
            *reinterpret_cast<unsigned int*>(
                Asb + row*128 + ((chq*4) ^ ((row&7)<<4))) = cvtpk(a[mt][0], a[mt][1]);
        }
        __syncthreads();   // A tile ready
        // ---- MFMA: this wave: 1 col-tile x TL3 row-tiles x 2 K-steps ----
        #pragma unroll
        for (int ks=0; ks<2; ++ks) {
            #pragma unroll
            for (int rt=0; rt<TL3; ++rt) {
                int arow = 16*rt + lr;
                short8 af = *reinterpret_cast<const short8*>(
                    Asb + arow*128 + ((16*lg + 64*ks) ^ ((arow&7)<<4)));
                cacc[rt] = __builtin_amdgcn_mfma_f32_16x16x32_bf16(
                    af, ks ? wf1 : wf0, cacc[rt], 0, 0, 0);
            }
        }
    }
}

template<int L3, int PI>
__device__ __forceinline__ void node_paths(
    const unsigned short* __restrict__ f1b, const unsigned short* __restrict__ f2b,
    const unsigned short* __restrict__ wt, const float* __restrict__ C2,
    float* C2s, unsigned char* Asb,
    int tid, int n0, int wid, int lr, int lg, f32x4 (&cacc)[2*L3+1])
{
    if constexpr (PI < C_NP[L3]) {
        node_pair<L3, PI>(f1b, f2b, wt, C2, C2s, Asb, tid, n0, wid, lr, lg, cacc);
        node_paths<L3, PI+1>(f1b, f2b, wt, C2, C2s, Asb, tid, n0, wid, lr, lg, cacc);
    }
}

template<int L3>
__device__ __forceinline__ void run16(
    int n0,
    const unsigned short* __restrict__ f1b, const unsigned short* __restrict__ f2b,
    const unsigned short* __restrict__ wt, const float* __restrict__ C2,
    float* __restrict__ out, float* C2s, unsigned char* Asb)
{
    constexpr int TL3 = 2*L3+1;
    const int tid  = threadIdx.x;
    const int lane = tid & 63, wid = tid >> 6;
    const int lr   = lane & 15, lg = lane >> 4;
    constexpr size_t OB = FOFF[L3];

    f32x4 cacc[TL3];
    #pragma unroll
    for (int rt=0; rt<TL3; ++rt) cacc[rt] = (f32x4){0.f,0.f,0.f,0.f};

    node_paths<L3, 0>(f1b, f2b, wt, C2, C2s, Asb, tid, n0, wid, lr, lg, cacc);

    // epilogue: residual (bf16 f1) + store. D: col=lane&15, row=4*(lane>>4)+i
    const unsigned short* __restrict__ fr = f1b + OB;
    const int col = 16*wid + lr;
    #pragma unroll
    for (int rt=0; rt<TL3; ++rt) {
        #pragma unroll
        for (int i=0;i<4;++i) {
            size_t ro = (size_t)(n0*TL3 + 16*rt + 4*lg + i) * K_DIM;
            float res = __uint_as_float((unsigned int)fr[ro + col] << 16);
            out[OB + ro + col] = res + cacc[rt][i];
        }
    }
}

__global__ __launch_bounds__(512, 4) void cg_main(
    const unsigned short* __restrict__ f1b, const unsigned short* __restrict__ f2b,
    const unsigned short* __restrict__ wt,
    const float* __restrict__ C2, float* __restrict__ out)
{
    __shared__ __align__(16) unsigned char Asb[14336];   // <=112 rows x 128B
    __shared__ float C2s[49];

    // Schedule: x = XCD (bid&7); j in [0,256): 16 rounds x 16 blocks
    // (4 per l3, each 16 nodes); one round covers the same 64-node slice for
    // all l3 -> L2-resident f reuse.
    int bid = blockIdx.x;
    int x = bid & 7, j = bid >> 3;
    int rnd = j >> 4, k = j & 15;
    int l3 = k >> 2, q = k & 3;
    int n0 = x*1024 + rnd*64 + q*16;
    if (l3 == 0)      run16<0>(n0, f1b, f2b, wt, C2, out, C2s, Asb);
    else if (l3 == 1) run16<1>(n0, f1b, f2b, wt, C2, out, C2s, Asb);
    else if (l3 == 2) run16<2>(n0, f1b, f2b, wt, C2, out, C2s, Asb);
    else              run16<3>(n0, f1b, f2b, wt, C2, out, C2s, Asb);
}

extern "C" void kernel_launch(void* const* d_in, const int* in_sizes, int n_in,
                              void* d_out, int out_size, void* d_ws, size_t ws_size,
                              hipStream_t stream) {
    const float* f10 = (const float*)d_in[0];
    const float* f20 = (const float*)d_in[1];
    const float* W0  = (const float*)d_in[2];
    const float* f11 = (const float*)d_in[3];
    const float* f21 = (const float*)d_in[4];
    const float* W1  = (const float*)d_in[5];
    const float* f12 = (const float*)d_in[6];
    const float* f22 = (const float*)d_in[7];
    const float* W2  = (const float*)d_in[8];
    const float* f13 = (const float*)d_in[9];
    const float* f23 = (const float*)d_in[10];
    const float* W3  = (const float*)d_in[11];

    float* C2 = (float*)d_ws;                                       // 6664 B
    unsigned short* wtw = (unsigned short*)((char*)d_ws + 8192);    // 1.09 MB
    unsigned short* f1b = (unsigned short*)((char*)d_ws + 1122304); // 32 MB
    unsigned short* f2b = f1b + FTOT;                               // 32 MB
    float* out = (float*)d_out;

    hipLaunchKernelGGL(cg_init, dim3(7), dim3(256), 0, stream, C2);
    hipLaunchKernelGGL(wt_prep, dim3(68*32), dim3(256), 0, stream, W0, W1, W2, W3, wtw);
    hipLaunchKernelGGL(fpack, dim3(7168, 8), dim3(256), 0, stream,
        f10, f11, f12, f13, f20, f21, f22, f23, f1b);
    hipLaunchKernelGGL(cg_main, dim3(2048), dim3(512), 0, stream,
        f1b, f2b, wtw, C2, out);
}

// Round 13
// 174.149 us; speedup vs baseline: 4.6836x; 1.1062x over previous
//
#include <hip/hip_runtime.h>

#define K_DIM 128

typedef __attribute__((ext_vector_type(8))) short short8;
typedef __attribute__((ext_vector_type(4))) float f32x4;

// ---- compile-time path tables: PATHS order = l1-major, l2, l3 ascending ----
constexpr int C_L1[34] = {0,0,0,0, 1,1,1,1,1,1,1,1,1, 2,2,2,2,2,2,2,2,2,2,2, 3,3,3,3,3,3,3,3,3,3};
constexpr int C_L2[34] = {0,1,2,3, 0,1,1,1,2,2,2,3,3, 0,1,1,1,2,2,2,2,3,3,3, 0,1,1,2,2,2,3,3,3,3};
constexpr int C_L3[34] = {0,1,2,3, 1,0,1,2,1,2,3,2,3, 2,1,2,3,0,1,2,3,1,2,3, 3,2,3,1,2,3,0,1,2,3};
constexpr int C_NP[4]  = {4,9,11,10};
constexpr int C_PL[4][11] = {
  {0,5,17,30, 0,0,0,0,0,0,0},
  {1,4,6,8,14,18,21,27,31, 0,0},
  {2,7,9,11,13,15,19,22,25,28,32},
  {3,10,12,16,20,23,24,26,29,33, 0}
};
constexpr int C_CSUM[4] = {0,8,26,48};      // 64-ch chunk base per l3
constexpr size_t FOFF[4] = {0, 1048576, 4194304, 9437184};  // per-l elem offsets
constexpr int FSZ[4] = {1048576, 3145728, 5242880, 7340032};
constexpr size_t FTOT = 16777216;           // elems per f-set

__device__ double dfactd(int n){ double r=1.0; for(int i=2;i<=n;++i) r*=(double)i; return r; }

__device__ __forceinline__ unsigned short f2bf(float x) {
    unsigned int b = __float_as_uint(x);
    return (unsigned short)((b + 0x7FFFu + ((b >> 16) & 1u)) >> 16);
}
__device__ __forceinline__ float bflo(unsigned int u){ return __uint_as_float(u << 16); }
__device__ __forceinline__ float bfhi(unsigned int u){ return __uint_as_float(u & 0xFFFF0000u); }

// packed RNE f32x2 -> bf16x2 (single VALU inst; pure-ALU asm)
__device__ __forceinline__ unsigned int cvtpk(float lo, float hi) {
    unsigned int r;
    asm("v_cvt_pk_bf16_f32 %0, %1, %2" : "=v"(r) : "v"(lo), "v"(hi));
    return r;
}

// C2[p][m1i][m2i], 34*49 floats at d_ws+0
__global__ void cg_init(float* __restrict__ C2) {
    int e = blockIdx.x*blockDim.x + threadIdx.x;
    if (e >= 34*49) return;
    int p = e/49, r = e%49, m1i = r/7, m2i = r%7;
    int l1 = C_L1[p], l2 = C_L2[p], l3 = C_L3[p];
    float val = 0.f;
    if (m1i < 2*l1+1 && m2i < 2*l2+1) {
        int m1 = m1i-l1, m2 = m2i-l2, m3 = m1+m2;
        if (m3 >= -l3 && m3 <= l3) {
            double pref = sqrt((double)(2*l3+1) * dfactd(l3+l1-l2)*dfactd(l3-l1+l2)
                               * dfactd(l1+l2-l3) / dfactd(l1+l2+l3+1));
            pref *= sqrt(dfactd(l3+m3)*dfactd(l3-m3)*dfactd(l1-m1)*dfactd(l1+m1)
                         *dfactd(l2-m2)*dfactd(l2+m2));
            int kmin = max(0, max(l2-l3-m1, l1-l3+m2));
            int kmax = min(l1+l2-l3, min(l1-m1, l2+m2));
            double s = 0.0;
            for (int k=kmin;k<=kmax;++k) {
                double t = dfactd(k)*dfactd(l1+l2-l3-k)*dfactd(l1-m1-k)
                         * dfactd(l2+m2-k)*dfactd(l3-l2+m1+k)*dfactd(l3-l1-m2+k);
                s += ((k&1)? -1.0:1.0)/t;
            }
            val = (float)(pref*s);
        }
    }
    C2[e] = val;
}

// W -> bf16 transposed+swizzled tiles: chunk c elem col*64 + (kk ^ ((col&7)<<3))
__global__ void wt_prep(const float* __restrict__ W0, const float* __restrict__ W1,
                        const float* __restrict__ W2, const float* __restrict__ W3,
                        unsigned short* __restrict__ wt) {
    int b = blockIdx.x;
    int chunk = b >> 5;
    int e = ((b & 31) << 8) + threadIdx.x;
    int kk = e & 63, col = e >> 6;
    int l3 = (chunk < 8) ? 0 : (chunk < 26) ? 1 : (chunk < 48) ? 2 : 3;
    int local = chunk - C_CSUM[l3];
    int kin = local*64 + kk;
    const float* W = (l3==0)?W0:(l3==1)?W1:(l3==2)?W2:W3;
    float v = W[(size_t)kin*K_DIM + col];
    wt[(size_t)chunk*8192 + col*64 + (kk ^ ((col&7)<<3))] = f2bf(v);
}

// f1/f2 -> bf16 packed copies in ws
__global__ void fpack(const float* __restrict__ s0, const float* __restrict__ s1,
                      const float* __restrict__ s2, const float* __restrict__ s3,
                      const float* __restrict__ s4, const float* __restrict__ s5,
                      const float* __restrict__ s6, const float* __restrict__ s7,
                      unsigned short* __restrict__ dst) {
    int y = blockIdx.y;
    int l = y & 3, fi = y >> 2;
    const float* srcs[8] = {s0,s1,s2,s3,s4,s5,s6,s7};
    const float* src = srcs[y];
    int i4 = blockIdx.x*256 + threadIdx.x;
    if (i4*4 >= FSZ[l]) return;
    float4 v = reinterpret_cast<const float4*>(src)[i4];
    unsigned int u0 = (unsigned int)f2bf(v.x) | ((unsigned int)f2bf(v.y) << 16);
    unsigned int u1 = (unsigned int)f2bf(v.z) | ((unsigned int)f2bf(v.w) << 16);
    unsigned short* d = dst + fi*FTOT + FOFF[l] + (size_t)i4*4;
    *reinterpret_cast<uint2*>(d) = make_uint2(u0, u1);
}

// One path, h-merged: TP pure-register (f resident), 128-ch swizzled A tile,
// 4 K-step MFMA with W frags from pre-swizzled global.
template<int L3, int PI>
__device__ __forceinline__ void res_path(
    const unsigned int (&q1)[16][2], const unsigned int (&q2)[16][2],
    const unsigned short* __restrict__ wt, const float* __restrict__ C2,
    float* C2s, unsigned char* Asb,
    int tid, int nodel, int chq, int wid, int lr, int lg, f32x4 (&cacc)[2*L3+1])
{
    constexpr int P  = C_PL[L3][PI];
    constexpr int l1 = C_L1[P], l2 = C_L2[P];
    constexpr int d1 = 2*l1+1, d2 = 2*l2+1;
    constexpr int TL3 = 2*L3+1;

    if (tid < 49) C2s[tid] = C2[P*49 + tid];
    __syncthreads();   // A free (prev MFMA done) + C2s visible

    // ---- W fragments: 4 K-steps from the 2 pre-swizzled 64-ch chunks ----
    const int col = 16*wid + lr;
    const int wkey = (col&7)<<4;
    const unsigned char* wb0 = (const unsigned char*)(wt + (size_t)(C_CSUM[L3] + PI*2    )*8192);
    const unsigned char* wb1 = (const unsigned char*)(wt + (size_t)(C_CSUM[L3] + PI*2 + 1)*8192);
    short8 wf[4];
    wf[0] = *reinterpret_cast<const short8*>(wb0 + col*128 + ((16*lg     ) ^ wkey));
    wf[1] = *reinterpret_cast<const short8*>(wb0 + col*128 + ((16*lg + 64) ^ wkey));
    wf[2] = *reinterpret_cast<const short8*>(wb1 + col*128 + ((16*lg     ) ^ wkey));
    wf[3] = *reinterpret_cast<const short8*>(wb1 + col*128 + ((16*lg + 64) ^ wkey));

    // ---- TP both halves from resident registers ----
    #pragma unroll
    for (int h=0; h<2; ++h) {
        float a[TL3][2];
        #pragma unroll
        for (int mt=0; mt<TL3; ++mt) { a[mt][0]=0.f; a[mt][1]=0.f; }
        #pragma unroll
        for (int m2i=0; m2i<d2; ++m2i) {
            float y0 = bflo(q2[l2*l2+m2i][h]);
            float y1 = bfhi(q2[l2*l2+m2i][h]);
            #pragma unroll
            for (int m1i=0; m1i<d1; ++m1i) {
                int mt = (m1i-l1) + (m2i-l2) + L3;
                if (mt >= 0 && mt < TL3) {      // folds at compile time
                    float c = C2s[m1i*7 + m2i];
                    a[mt][0] = fmaf(c*bflo(q1[l1*l1+m1i][h]), y0, a[mt][0]);
                    a[mt][1] = fmaf(c*bfhi(q1[l1*l1+m1i][h]), y1, a[mt][1]);
                }
            }
        }
        #pragma unroll
        for (int mt=0; mt<TL3; ++mt) {
            int row = nodel*TL3 + mt;
            *reinterpret_cast<unsigned int*>(
                Asb + row*256 + h*128 + ((chq*4) ^ ((row&7)<<4))) = cvtpk(a[mt][0], a[mt][1]);
        }
    }
    __syncthreads();   // A tile ready

    // ---- MFMA: 4 K-steps x TL3 row-tiles, 1 col-tile per wave ----
    #pragma unroll
    for (int kst=0; kst<4; ++kst) {
        #pragma unroll
        for (int rt=0; rt<TL3; ++rt) {
            int arow = 16*rt + lr;
            short8 af = *reinterpret_cast<const short8*>(
                Asb + arow*256 + ((16*lg + 64*kst) ^ ((arow&7)<<4)));
            cacc[rt] = __builtin_amdgcn_mfma_f32_16x16x32_bf16(af, wf[kst], cacc[rt], 0, 0, 0);
        }
    }
}

template<int L3, int PI>
__device__ __forceinline__ void res_paths(
    const unsigned int (&q1)[16][2], const unsigned int (&q2)[16][2],
    const unsigned short* __restrict__ wt, const float* __restrict__ C2,
    float* C2s, unsigned char* Asb,
    int tid, int nodel, int chq, int wid, int lr, int lg, f32x4 (&cacc)[2*L3+1])
{
    if constexpr (PI < C_NP[L3]) {
        res_path<L3, PI>(q1, q2, wt, C2, C2s, Asb, tid, nodel, chq, wid, lr, lg, cacc);
        res_paths<L3, PI+1>(q1, q2, wt, C2, C2s, Asb, tid, nodel, chq, wid, lr, lg, cacc);
    }
}

template<int L3>
__device__ __forceinline__ void run16(
    int n0,
    const unsigned short* __restrict__ f1b, const unsigned short* __restrict__ f2b,
    const unsigned short* __restrict__ wt, const float* __restrict__ C2,
    float* __restrict__ out, float* C2s, unsigned char* Asb)
{
    constexpr int TL3 = 2*L3+1;
    const int tid   = threadIdx.x;
    const int nodel = tid >> 5;       // 0..15
    const int chq   = tid & 31;       // 2-ch chunk
    const int lane  = tid & 63, wid = tid >> 6;
    const int lr    = lane & 15, lg = lane >> 4;
    constexpr size_t OB = FOFF[L3];

    // ---- prologue: load ALL f rows for this node/chq into registers ----
    unsigned int q1[16][2], q2[16][2];
    #pragma unroll
    for (int l=0; l<4; ++l) {
        const unsigned short* g1 = f1b + FOFF[l] + (size_t)(n0+nodel)*((2*l+1)*128) + chq*2;
        const unsigned short* g2 = f2b + FOFF[l] + (size_t)(n0+nodel)*((2*l+1)*128) + chq*2;
        #pragma unroll
        for (int m=0; m<2*l+1; ++m) {
            #pragma unroll
            for (int h=0; h<2; ++h) {
                q1[l*l+m][h] = *reinterpret_cast<const unsigned int*>(g1 + m*128 + h*64);
                q2[l*l+m][h] = *reinterpret_cast<const unsigned int*>(g2 + m*128 + h*64);
            }
        }
    }

    f32x4 cacc[TL3];
    #pragma unroll
    for (int rt=0; rt<TL3; ++rt) cacc[rt] = (f32x4){0.f,0.f,0.f,0.f};

    res_paths<L3, 0>(q1, q2, wt, C2, C2s, Asb, tid, nodel, chq, wid, lr, lg, cacc);

    // ---- epilogue: LDS restage -> full-line coalesced store + residual ----
    __syncthreads();                   // last MFMA done reading Asb
    float* S = reinterpret_cast<float*>(Asb);
    const unsigned short* __restrict__ fr = f1b + OB;
    const int col = 16*wid + lr;
    const int rr = tid >> 5, c0 = (tid & 31) * 4;
    #pragma unroll
    for (int rt=0; rt<TL3; ++rt) {
        #pragma unroll
        for (int i=0;i<4;++i)
            S[(4*lg+i)*128 + col] = cacc[rt][i];
        __syncthreads();
        {
            size_t ro = (size_t)(n0*TL3 + 16*rt + rr) * K_DIM;
            float4 v = *reinterpret_cast<const float4*>(&S[rr*128 + c0]);
            uint2 rb = *reinterpret_cast<const uint2*>(fr + ro + c0);
            v.x += bflo(rb.x); v.y += bfhi(rb.x);
            v.z += bflo(rb.y); v.w += bfhi(rb.y);
            *reinterpret_cast<float4*>(&out[OB + ro + c0]) = v;
        }
        __syncthreads();
    }
}

__global__ __launch_bounds__(512, 2) void cg_main(
    const unsigned short* __restrict__ f1b, const unsigned short* __restrict__ f2b,
    const unsigned short* __restrict__ wt,
    const float* __restrict__ C2, float* __restrict__ out)
{
    __shared__ __align__(16) unsigned char Asb[28672];   // <=112 rows x 256B
    __shared__ float C2s[49];

    // Schedule: x = XCD (bid&7); 16 rounds x 16 blocks (4 per l3, 16 nodes each);
    // one round covers the same 64-node slice for all l3 -> L2-resident f reuse.
    int bid = blockIdx.x;
    int x = bid & 7, j = bid >> 3;
    int rnd = j >> 4, k = j & 15;
    int l3 = k >> 2, q = k & 3;
    int n0 = x*1024 + rnd*64 + q*16;
    if (l3 == 0)      run16<0>(n0, f1b, f2b, wt, C2, out, C2s, Asb);
    else if (l3 == 1) run16<1>(n0, f1b, f2b, wt, C2, out, C2s, Asb);
    else if (l3 == 2) run16<2>(n0, f1b, f2b, wt, C2, out, C2s, Asb);
    else              run16<3>(n0, f1b, f2b, wt, C2, out, C2s, Asb);
}

extern "C" void kernel_launch(void* const* d_in, const int* in_sizes, int n_in,
                              void* d_out, int out_size, void* d_ws, size_t ws_size,
                              hipStream_t stream) {
    const float* f10 = (const float*)d_in[0];
    const float* f20 = (const float*)d_in[1];
    const float* W0  = (const float*)d_in[2];
    const float* f11 = (const float*)d_in[3];
    const float* f21 = (const float*)d_in[4];
    const float* W1  = (const float*)d_in[5];
    const float* f12 = (const float*)d_in[6];
    const float* f22 = (const float*)d_in[7];
    const float* W2  = (const float*)d_in[8];
    const float* f13 = (const float*)d_in[9];
    const float* f23 = (const float*)d_in[10];
    const float* W3  = (const float*)d_in[11];

    float* C2 = (float*)d_ws;                                       // 6664 B
    unsigned short* wtw = (unsigned short*)((char*)d_ws + 8192);    // 1.09 MB
    unsigned short* f1b = (unsigned short*)((char*)d_ws + 1122304); // 32 MB
    unsigned short* f2b = f1b + FTOT;                               // 32 MB
    float* out = (float*)d_out;

    hipLaunchKernelGGL(cg_init, dim3(7), dim3(256), 0, stream, C2);
    hipLaunchKernelGGL(wt_prep, dim3(68*32), dim3(256), 0, stream, W0, W1, W2, W3, wtw);
    hipLaunchKernelGGL(fpack, dim3(7168, 8), dim3(256), 0, stream,
        f10, f11, f12, f13, f20, f21, f22, f23, f1b);
    hipLaunchKernelGGL(cg_main, dim3(2048), dim3(512), 0, stream,
        f1b, f2b, wtw, C2, out);
}

// Round 15
// 159.571 us; speedup vs baseline: 5.1115x; 1.0914x over previous
//
#include <hip/hip_runtime.h>

#define K_DIM 128

typedef __attribute__((ext_vector_type(8))) short short8;
typedef __attribute__((ext_vector_type(4))) float f32x4;

// ---- compile-time path tables: PATHS order = l1-major, l2, l3 ascending ----
constexpr int C_L1[34] = {0,0,0,0, 1,1,1,1,1,1,1,1,1, 2,2,2,2,2,2,2,2,2,2,2, 3,3,3,3,3,3,3,3,3,3};
constexpr int C_L2[34] = {0,1,2,3, 0,1,1,1,2,2,2,3,3, 0,1,1,1,2,2,2,2,3,3,3, 0,1,1,2,2,2,3,3,3,3};
constexpr int C_L3[34] = {0,1,2,3, 1,0,1,2,1,2,3,2,3, 2,1,2,3,0,1,2,3,1,2,3, 3,2,3,1,2,3,0,1,2,3};
constexpr int C_NP[4]  = {4,9,11,10};
constexpr int C_PL[4][11] = {
  {0,5,17,30, 0,0,0,0,0,0,0},
  {1,4,6,8,14,18,21,27,31, 0,0},
  {2,7,9,11,13,15,19,22,25,28,32},
  {3,10,12,16,20,23,24,26,29,33, 0}
};
constexpr int C_CSUM[4] = {0,8,26,48};      // 64-ch chunk base per l3
constexpr size_t FOFF[4] = {0, 1048576, 4194304, 9437184};  // per-l elem offsets
constexpr int FSZ[4] = {1048576, 3145728, 5242880, 7340032};
constexpr size_t FTOT = 16777216;           // elems per f-set

__device__ double dfactd(int n){ double r=1.0; for(int i=2;i<=n;++i) r*=(double)i; return r; }

__device__ __forceinline__ unsigned short f2bf(float x) {
    unsigned int b = __float_as_uint(x);
    return (unsigned short)((b + 0x7FFFu + ((b >> 16) & 1u)) >> 16);
}
__device__ __forceinline__ float bflo(unsigned int u){ return __uint_as_float(u << 16); }
__device__ __forceinline__ float bfhi(unsigned int u){ return __uint_as_float(u & 0xFFFF0000u); }

__device__ __forceinline__ unsigned int cvtpk(float lo, float hi) {
    unsigned int r;
    asm("v_cvt_pk_bf16_f32 %0, %1, %2" : "=v"(r) : "v"(lo), "v"(hi));
    return r;
}

// C2[p][m1i][m2i], 34*49 floats at d_ws+0
__global__ void cg_init(float* __restrict__ C2) {
    int e = blockIdx.x*blockDim.x + threadIdx.x;
    if (e >= 34*49) return;
    int p = e/49, r = e%49, m1i = r/7, m2i = r%7;
    int l1 = C_L1[p], l2 = C_L2[p], l3 = C_L3[p];
    float val = 0.f;
    if (m1i < 2*l1+1 && m2i < 2*l2+1) {
        int m1 = m1i-l1, m2 = m2i-l2, m3 = m1+m2;
        if (m3 >= -l3 && m3 <= l3) {
            double pref = sqrt((double)(2*l3+1) * dfactd(l3+l1-l2)*dfactd(l3-l1+l2)
                               * dfactd(l1+l2-l3) / dfactd(l1+l2+l3+1));
            pref *= sqrt(dfactd(l3+m3)*dfactd(l3-m3)*dfactd(l1-m1)*dfactd(l1+m1)
                         *dfactd(l2-m2)*dfactd(l2+m2));
            int kmin = max(0, max(l2-l3-m1, l1-l3+m2));
            int kmax = min(l1+l2-l3, min(l1-m1, l2+m2));
            double s = 0.0;
            for (int k=kmin;k<=kmax;++k) {
                double t = dfactd(k)*dfactd(l1+l2-l3-k)*dfactd(l1-m1-k)
                         * dfactd(l2+m2-k)*dfactd(l3-l2+m1+k)*dfactd(l3-l1-m2+k);
                s += ((k&1)? -1.0:1.0)/t;
            }
            val = (float)(pref*s);
        }
    }
    C2[e] = val;
}

// W -> bf16 transposed+swizzled tiles: chunk c elem col*64 + (kk ^ ((col&7)<<3))
__global__ void wt_prep(const float* __restrict__ W0, const float* __restrict__ W1,
                        const float* __restrict__ W2, const float* __restrict__ W3,
                        unsigned short* __restrict__ wt) {
    int b = blockIdx.x;
    int chunk = b >> 5;
    int e = ((b & 31) << 8) + threadIdx.x;
    int kk = e & 63, col = e >> 6;
    int l3 = (chunk < 8) ? 0 : (chunk < 26) ? 1 : (chunk < 48) ? 2 : 3;
    int local = chunk - C_CSUM[l3];
    int kin = local*64 + kk;
    const float* W = (l3==0)?W0:(l3==1)?W1:(l3==2)?W2:W3;
    float v = W[(size_t)kin*K_DIM + col];
    wt[(size_t)chunk*8192 + col*64 + (kk ^ ((col&7)<<3))] = f2bf(v);
}

// f1/f2 -> bf16 packed copies in ws
__global__ void fpack(const float* __restrict__ s0, const float* __restrict__ s1,
                      const float* __restrict__ s2, const float* __restrict__ s3,
                      const float* __restrict__ s4, const float* __restrict__ s5,
                      const float* __restrict__ s6, const float* __restrict__ s7,
                      unsigned short* __restrict__ dst) {
    int y = blockIdx.y;
    int l = y & 3, fi = y >> 2;
    const float* srcs[8] = {s0,s1,s2,s3,s4,s5,s6,s7};
    const float* src = srcs[y];
    int i4 = blockIdx.x*256 + threadIdx.x;
    if (i4*4 >= FSZ[l]) return;
    float4 v = reinterpret_cast<const float4*>(src)[i4];
    unsigned int u0 = (unsigned int)f2bf(v.x) | ((unsigned int)f2bf(v.y) << 16);
    unsigned int u1 = (unsigned int)f2bf(v.z) | ((unsigned int)f2bf(v.w) << 16);
    unsigned short* d = dst + fi*FTOT + FOFF[l] + (size_t)i4*4;
    *reinterpret_cast<uint2*>(d) = make_uint2(u0, u1);
}

// TP for one path (both halves) from resident regs into swizzled A buffer.
template<int L3, int PI>
__device__ __forceinline__ void tp_into(
    const unsigned int (&q1)[16][2], const unsigned int (&q2)[16][2],
    const float* __restrict__ C2slot, unsigned char* __restrict__ Ab,
    int nodel, int chq)
{
    constexpr int P  = C_PL[L3][PI];
    constexpr int l1 = C_L1[P], l2 = C_L2[P];
    constexpr int d1 = 2*l1+1, d2 = 2*l2+1;
    constexpr int TL3 = 2*L3+1;
    #pragma unroll
    for (int h=0; h<2; ++h) {
        float xlo[d1], xhi[d1];                    // pre-extract once
        #pragma unroll
        for (int m=0;m<d1;++m) { xlo[m]=bflo(q1[l1*l1+m][h]); xhi[m]=bfhi(q1[l1*l1+m][h]); }
        float a[TL3][2];
        #pragma unroll
        for (int mt=0;mt<TL3;++mt){ a[mt][0]=0.f; a[mt][1]=0.f; }
        #pragma unroll
        for (int m2i=0; m2i<d2; ++m2i) {
            float y0 = bflo(q2[l2*l2+m2i][h]);
            float y1 = bfhi(q2[l2*l2+m2i][h]);
            #pragma unroll
            for (int m1i=0; m1i<d1; ++m1i) {
                int mt = (m1i-l1) + (m2i-l2) + L3;
                if (mt >= 0 && mt < TL3) {         // folds at compile time
                    float c = C2slot[m1i*7 + m2i];
                    a[mt][0] = fmaf(c*xlo[m1i], y0, a[mt][0]);
                    a[mt][1] = fmaf(c*xhi[m1i], y1, a[mt][1]);
                }
            }
        }
        #pragma unroll
        for (int mt=0; mt<TL3; ++mt) {
            int row = nodel*TL3 + mt;
            *reinterpret_cast<unsigned int*>(
                Ab + row*256 + h*128 + ((chq*4) ^ ((row&7)<<4))) = cvtpk(a[mt][0], a[mt][1]);
        }
    }
}

template<int L3, int PI>
__device__ __forceinline__ void load_wf(const unsigned short* __restrict__ wt,
                                        int col, int lg, short8 (&wf)[4]) {
    const int wkey = (col&7)<<4;
    const unsigned char* wb0 = (const unsigned char*)(wt + (size_t)(C_CSUM[L3] + PI*2    )*8192);
    const unsigned char* wb1 = (const unsigned char*)(wt + (size_t)(C_CSUM[L3] + PI*2 + 1)*8192);
    wf[0] = *reinterpret_cast<const short8*>(wb0 + col*128 + ((16*lg     ) ^ wkey));
    wf[1] = *reinterpret_cast<const short8*>(wb0 + col*128 + ((16*lg + 64) ^ wkey));
    wf[2] = *reinterpret_cast<const short8*>(wb1 + col*128 + ((16*lg     ) ^ wkey));
    wf[3] = *reinterpret_cast<const short8*>(wb1 + col*128 + ((16*lg + 64) ^ wkey));
}

template<int L3>
__device__ __forceinline__ void mfma_from(
    const unsigned char* __restrict__ Ab, const short8 (&wf)[4],
    int lr, int lg, f32x4 (&cacc)[2*L3+1])
{
    constexpr int TL3 = 2*L3+1;
    #pragma unroll
    for (int kst=0; kst<4; ++kst) {
        #pragma unroll
        for (int rt=0; rt<TL3; ++rt) {
            int arow = 16*rt + lr;
            short8 af = *reinterpret_cast<const short8*>(
                Ab + arow*256 + ((16*lg + 64*kst) ^ ((arow&7)<<4)));
            cacc[rt] = __builtin_amdgcn_mfma_f32_16x16x32_bf16(af, wf[kst], cacc[rt], 0, 0, 0);
        }
    }
}

// Pipelined path chain: iteration PI = {wf(PI), C2s(PI+2) preload,
// TP(PI+1)->buf[(PI+1)&1], MFMA(PI)<-buf[PI&1], barrier}.
template<int L3, int PI>
__device__ __forceinline__ void pipe(
    const unsigned int (&q1)[16][2], const unsigned int (&q2)[16][2],
    const unsigned short* __restrict__ wt, const float* __restrict__ C2,
    float (&C2s)[2][49], unsigned char* A0, unsigned char* A1,
    int tid, int nodel, int chq, int col, int lr, int lg, f32x4 (&cacc)[2*L3+1])
{
    constexpr int NP = C_NP[L3];
    short8 wf[4];
    load_wf<L3, PI>(wt, col, lg, wf);
    if constexpr (PI+2 < NP) {
        if (tid < 49) C2s[PI&1][tid] = C2[C_PL[L3][PI+2]*49 + tid];
    }
    if constexpr (PI+1 < NP)
        tp_into<L3, PI+1>(q1, q2, C2s[(PI+1)&1], ((PI+1)&1) ? A1 : A0, nodel, chq);
    mfma_from<L3>((PI&1) ? A1 : A0, wf, lr, lg, cacc);
    __syncthreads();
    if constexpr (PI+1 < NP)
        pipe<L3, PI+1>(q1, q2, wt, C2, C2s, A0, A1, tid, nodel, chq, col, lr, lg, cacc);
}

template<int L3>
__device__ __forceinline__ void run16(
    int n0,
    const unsigned short* __restrict__ f1b, const unsigned short* __restrict__ f2b,
    const unsigned short* __restrict__ wt, const float* __restrict__ C2,
    float* __restrict__ out, float (&C2s)[2][49], unsigned char* Asb)
{
    constexpr int TL3 = 2*L3+1;
    constexpr int NP  = C_NP[L3];
    const int tid   = threadIdx.x;
    const int nodel = tid >> 5;
    const int chq   = tid & 31;
    const int lane  = tid & 63, wid = tid >> 6;
    const int lr    = lane & 15, lg = lane >> 4;
    const int col   = 16*wid + lr;
    constexpr size_t OB = FOFF[L3];
    unsigned char* A0 = Asb;
    unsigned char* A1 = Asb + 28672;

    // prologue: resident f loads (all rows, once)
    unsigned int q1[16][2], q2[16][2];
    #pragma unroll
    for (int l=0; l<4; ++l) {
        const unsigned short* g1 = f1b + FOFF[l] + (size_t)(n0+nodel)*((2*l+1)*128) + chq*2;
        const unsigned short* g2 = f2b + FOFF[l] + (size_t)(n0+nodel)*((2*l+1)*128) + chq*2;
        #pragma unroll
        for (int m=0; m<2*l+1; ++m) {
            #pragma unroll
            for (int h=0; h<2; ++h) {
                q1[l*l+m][h] = *reinterpret_cast<const unsigned int*>(g1 + m*128 + h*64);
                q2[l*l+m][h] = *reinterpret_cast<const unsigned int*>(g2 + m*128 + h*64);
            }
        }
    }

    f32x4 cacc[TL3];
    #pragma unroll
    for (int rt=0; rt<TL3; ++rt) cacc[rt] = (f32x4){0.f,0.f,0.f,0.f};

    if (tid < 49) {
        C2s[0][tid] = C2[C_PL[L3][0]*49 + tid];
        if constexpr (NP > 1) C2s[1][tid] = C2[C_PL[L3][1]*49 + tid];
    }
    __syncthreads();
    tp_into<L3, 0>(q1, q2, C2s[0], A0, nodel, chq);
    __syncthreads();
    pipe<L3, 0>(q1, q2, wt, C2, C2s, A0, A1, tid, nodel, chq, col, lr, lg, cacc);

    // epilogue: padded LDS restage (stride 132) in 4-row-tile batches ->
    // full-line coalesced stores + bf16 residual
    float* S = reinterpret_cast<float*>(Asb);
    const unsigned short* __restrict__ fr = f1b + OB;
    #pragma unroll
    for (int rt0=0; rt0<TL3; rt0+=4) {
        const int bn = (TL3 - rt0 < 4) ? (TL3 - rt0) : 4;
        #pragma unroll
        for (int rtl=0; rtl<4; ++rtl) {
            if (rtl < bn) {
                #pragma unroll
                for (int i=0;i<4;++i)
                    S[(rtl*16 + 4*lg + i)*132 + col] = cacc[rt0+rtl][i];
            }
        }
        __syncthreads();
        #pragma unroll
        for (int it=0; it<4; ++it) {
            if (it < bn) {
                int s = tid + it*512;
                int rows = s >> 5, cq = (s & 31) * 4;
                int gr = n0*TL3 + (rt0 + (rows >> 4))*16 + (rows & 15);
                size_t ro = (size_t)gr * K_DIM;
                float4 v = *reinterpret_cast<const float4*>(&S[rows*132 + cq]);
                uint2 rb = *reinterpret_cast<const uint2*>(fr + ro + cq);
                v.x += bflo(rb.x); v.y += bfhi(rb.x);
                v.z += bflo(rb.y); v.w += bfhi(rb.y);
                *reinterpret_cast<float4*>(&out[OB + ro + cq]) = v;
            }
        }
        __syncthreads();
    }
}

__global__ __launch_bounds__(512, 2) void cg_main(
    const unsigned short* __restrict__ f1b, const unsigned short* __restrict__ f2b,
    const unsigned short* __restrict__ wt,
    const float* __restrict__ C2, float* __restrict__ out)
{
    __shared__ __align__(16) unsigned char Asb[2*28672];  // A dbuf / epilogue stage
    __shared__ float C2s[2][49];

    // Schedule: x = XCD (bid&7); 16 rounds x 16 blocks (4 per l3, 16 nodes each);
    // one round covers the same 64-node slice for all l3 -> L2-resident f reuse.
    int bid = blockIdx.x;
    int x = bid & 7, j = bid >> 3;
    int rnd = j >> 4, k = j & 15;
    int l3 = k >> 2, q = k & 3;
    int n0 = x*1024 + rnd*64 + q*16;
    if (l3 == 0)      run16<0>(n0, f1b, f2b, wt, C2, out, C2s, Asb);
    else if (l3 == 1) run16<1>(n0, f1b, f2b, wt, C2, out, C2s, Asb);
    else if (l3 == 2) run16<2>(n0, f1b, f2b, wt, C2, out, C2s, Asb);
    else              run16<3>(n0, f1b, f2b, wt, C2, out, C2s, Asb);
}

extern "C" void kernel_launch(void* const* d_in, const int* in_sizes, int n_in,
                              void* d_out, int out_size, void* d_ws, size_t ws_size,
                              hipStream_t stream) {
    const float* f10 = (const float*)d_in[0];
    const float* f20 = (const float*)d_in[1];
    const float* W0  = (const float*)d_in[2];
    const float* f11 = (const float*)d_in[3];
    const float* f21 = (const float*)d_in[4];
    const float* W1  = (const float*)d_in[5];
    const float* f12 = (const float*)d_in[6];
    const float* f22 = (const float*)d_in[7];
    const float* W2  = (const float*)d_in[8];
    const float* f13 = (const float*)d_in[9];
    const float* f23 = (const float*)d_in[10];
    const float* W3  = (const float*)d_in[11];

    float* C2 = (float*)d_ws;                                       // 6664 B
    unsigned short* wtw = (unsigned short*)((char*)d_ws + 8192);    // 1.09 MB
    unsigned short* f1b = (unsigned short*)((char*)d_ws + 1122304); // 32 MB
    unsigned short* f2b = f1b + FTOT;                               // 32 MB
    float* out = (float*)d_out;

    hipLaunchKernelGGL(cg_init, dim3(7), dim3(256), 0, stream, C2);
    hipLaunchKernelGGL(wt_prep, dim3(68*32), dim3(256), 0, stream, W0, W1, W2, W3, wtw);
    hipLaunchKernelGGL(fpack, dim3(7168, 8), dim3(256), 0, stream,
        f10, f11, f12, f13, f20, f21, f22, f23, f1b);
    hipLaunchKernelGGL(cg_main, dim3(2048), dim3(512), 0, stream,
        f1b, f2b, wtw, C2, out);
}